// Round 15
// baseline (286.744 us; speedup 1.0000x reference)
//
#include <hip/hip_runtime.h>
#include <hip/hip_bf16.h>

// B=64 (LSTM time axis via torch batch_first quirk), L=64 (only col 63 used),
// N=256, C=8, Ct=4 -> NQ=1024 sequences, H=128, 4H=512, RH1=128, RH2=64, S=4.
//
// fp16 scheme (R14, passing at 1.95e-3): fp16 operands everywhere, fp32 accum.
// R15: LSTM step critical path shortened: (a) x-plane MFMAs (acc_x = bsum +
// x(t+1).W_ih) issue in the barrier shadow - off the critical path; (b) h-plane
// chain split 4 -> 2||2 joined by a scalar add (only C-reg 0 is used).
// Prep kernels merged into one; MLP occupancy 2 -> 3 blocks/CU.

typedef __attribute__((ext_vector_type(8))) _Float16 half8;  // 8 f16, 4 VGPRs
typedef __attribute__((ext_vector_type(4))) float f32x4;

#define MFMAH(a, b, c) __builtin_amdgcn_mfma_f32_16x16x32_f16(a, b, c, 0, 0, 0)

__device__ __forceinline__ float sigf(float x)   { return 1.0f / (1.0f + __expf(-x)); }
__device__ __forceinline__ float tanh_f(float x) { return 1.0f - 2.0f / (__expf(2.0f * x) + 1.0f); }

// ---------------- one merged prep kernel ----------------
// segments: [0,524288) init_cur | [..,+2097152) hi16 | wp1 32768 | wp2 8192 |
// wp3 1024 | wpB 81920.  Total 2745344 = 10724 * 256.
__global__ void prep_k(const float* __restrict__ x, const float* __restrict__ hi,
                       const float* __restrict__ W1, const float* __restrict__ W2,
                       const float* __restrict__ W3, const float* __restrict__ W_hh,
                       const float* __restrict__ W_ih,
                       _Float16* __restrict__ cur16, _Float16* __restrict__ hi16,
                       _Float16* __restrict__ wp1, _Float16* __restrict__ wp2,
                       _Float16* __restrict__ wp3, _Float16* __restrict__ wpB)
{
    int i = blockIdx.x * 256 + threadIdx.x;
    if (i < 524288) {                                   // cur16 <- x[:,63,:,:]
        int b = i >> 13, rem = i & 8191;
        cur16[i] = (_Float16)x[(size_t)b * 524288 + 63 * 8192 + rem];
        return;
    }
    i -= 524288;
    if (i < 2097152) { hi16[i] = (_Float16)hi[i]; return; }
    i -= 2097152;
    if (i < 32768) {                       // wp1 [kt8][nt8][512]; K=256 = [hs|hi]
        int fragid = i >> 9, lj = i & 511;
        int kt = fragid >> 3, nt = fragid & 7;
        int l = lj >> 3, j = lj & 7;
        int k = kt * 32 + (l >> 4) * 8 + j;
        int o = nt * 16 + (l & 15);
        wp1[i] = (_Float16)W1[o * 257 + k];
        return;
    }
    i -= 32768;
    if (i < 8192) {                        // wp2 [kt4][nt4][512]; K=128
        int fragid = i >> 9, lj = i & 511;
        int kt = fragid >> 2, nt = fragid & 3;
        int l = lj >> 3, j = lj & 7;
        int k = kt * 32 + (l >> 4) * 8 + j;
        int o = nt * 16 + (l & 15);
        wp2[i] = (_Float16)W2[o * 128 + k];
        return;
    }
    i -= 8192;
    if (i < 1024) {                        // wp3 [kt2][512]; K=64
        int kt = i >> 9, lj = i & 511;
        int l = lj >> 3, j = lj & 7;
        int k = kt * 32 + (l >> 4) * 8 + j;
        int c = l & 15;
        wp3[i] = (_Float16)((c < 8) ? W3[c * 64 + k] : 0.0f);
        return;
    }
    i -= 1024;
    if (i < 81920) {                       // wpB [kt5][ntile32][512]
        int frag = i >> 9, lj = i & 511;
        int kt = frag >> 5, ntile = frag & 31;
        int l = lj >> 3, j = lj & 7;
        int klocal = (l >> 4) * 8 + j;
        int col = ntile * 16 + (l & 15);
        float v;
        if (kt < 4) v = W_hh[col * 128 + kt * 32 + klocal];
        else        v = (klocal < 8) ? W_ih[col * 8 + klocal] : 0.0f;
        wpB[i] = (_Float16)v;
    }
}

// ---------------- LSTM scan: fp16 MFMA, 256 blocks -------------
// 256 wgs x 512 thr (8 waves = col-groups). wg owns 4 sequences at M-rows
// {0,4,8,12}. Wave cg computes gate cols g*128 + cg*16 + (l&15), g=0..3.
// C-reg 0 of lane (lk,li) = preact of item (seq=lk, col=cg*16+li).
// Per step: acc_x (x-plane, 4 MFMA) precomputed in the previous barrier
// shadow; h-planes split into two 2-deep chains joined by a scalar add.
// A-frag reads broadcast per 4-lane group (li&12); x staged once in LDS;
// hs stored register-direct; in-loop barrier drains lgkmcnt only.
__global__ __launch_bounds__(512, 2) void lstm_mfma_k(
    const _Float16* __restrict__ cur16, const _Float16* __restrict__ wpB,
    const float* __restrict__ b_ih, const float* __restrict__ b_hh,
    _Float16* __restrict__ hs16)
{
    __shared__ __align__(16) _Float16 zone[2][4][640];   // 10 KB h planes
    __shared__ __align__(16) _Float16 xz[64][32];        // 4 KB x slice

    const int t  = threadIdx.x;
    const int cg = t >> 6, l = t & 63;
    const int li = l & 15, lk = l >> 4;
    const int q0 = blockIdx.x * 4;

    // B-frags: 4 gates x 5 planes (4 Whh + 1 x) = 80 regs -> pinned AGPRs
    half8 bw[4][5];
#pragma unroll
    for (int g = 0; g < 4; ++g)
#pragma unroll
        for (int kt = 0; kt < 5; ++kt) {
            bw[g][kt] = *(const half8*)(wpB + (size_t)(kt * 32 + g * 8 + cg) * 512 + l * 8);
            asm volatile("" : "+a"(bw[g][kt]));   // pin to AGPR class, no remat
        }

    f32x4 bs4[4];
#pragma unroll
    for (int g = 0; g < 4; ++g) {
        int gc = g * 128 + cg * 16 + li;
        float bv = b_ih[gc] + b_hh[gc];
        bs4[g] = (f32x4){bv, bv, bv, bv};
    }

    for (int i = t; i < 1280; i += 512) ((uint*)zone)[i] = 0;   // both bufs = 0
    // stage this block's entire x slice: 64 steps x 4 seqs x 8 c (fp16) = 4 KB
    if (t < 256) {
        int step = t >> 2, tt = t & 3;
        *(uint4*)&xz[step][tt * 8] =
            *(const uint4*)(cur16 + (size_t)step * 8192 + q0 * 8 + tt * 8);
    }
    float cc = 0.0f;
    __syncthreads();

    const int zpl   = cg >> 1;                // this wave's h plane
    const int jl    = (cg & 1) * 16 + li;
    // BROADCAST read offset: pad lanes read their group's real row (li&12)
    const int roff  = (li & 12) * 40 + lk * 8;
    const int srow  = lk * 4;                 // this lane's item row (seq lk)

    // register-direct hs store pointer: lane (cg,lk,li) owns
    // hs[seq = q0+lk][col = cg*16+li]
    _Float16* ph = hs16 + (size_t)(q0 + lk) * 128 + cg * 16 + li;
    // x A-frag LDS address: row li -> seq li>>2 (broadcast); lk>=1 lanes pair
    // with zero B rows, any finite value is fine.
    const _Float16* xrd = &xz[0][(li >> 2) * 8];

    // acc_x for step 0 (x-plane + bias): off the loop critical path
    f32x4 accx[4];
    {
        half8 xa0 = *(const half8*)(xrd);
#pragma unroll
        for (int g = 0; g < 4; ++g)
            accx[g] = MFMAH(xa0, bw[g][4], bs4[g]);
    }

    auto dostep = [&](int step, int p) {
        const int pn = p ^ 1;

        half8 ah[4];
#pragma unroll
        for (int kt = 0; kt < 4; ++kt)
            ah[kt] = *(const half8*)&zone[p][kt][roff];

        const f32x4 z4 = (f32x4){0.0f, 0.0f, 0.0f, 0.0f};
        f32x4 a0[4], a1[4];
#pragma unroll
        for (int g = 0; g < 4; ++g) {
            a0[g] = MFMAH(ah[0], bw[g][0], accx[g]);
            a1[g] = MFMAH(ah[2], bw[g][2], z4);
        }
#pragma unroll
        for (int g = 0; g < 4; ++g) {
            a0[g] = MFMAH(ah[1], bw[g][1], a0[g]);
            a1[g] = MFMAH(ah[3], bw[g][3], a1[g]);
        }

        // gate math (torch order i,f,g,o): ONE packed item per lane (reg 0)
        float pi = a0[0][0] + a1[0][0];
        float pf = a0[1][0] + a1[1][0];
        float pg = a0[2][0] + a1[2][0];
        float po = a0[3][0] + a1[3][0];
        cc = sigf(pf) * cc + sigf(pi) * tanh_f(pg);
        float hv = sigf(po) * tanh_f(cc);
        _Float16 h16 = (_Float16)hv;
        zone[pn][zpl][srow * 40 + jl] = h16;
        // register-direct, fire-and-forget hs store
        ph[(size_t)step * 131072] = h16;
        // drain LDS only; global stores stay in flight
        asm volatile("s_waitcnt lgkmcnt(0)\n\ts_barrier" ::: "memory");

        // barrier shadow: start next step's x-plane accumulation (independent
        // of zone) while the next iteration's ds_reads are issued.
        half8 xn = *(const half8*)(xrd + ((step + 1) & 63) * 32);
#pragma unroll
        for (int g = 0; g < 4; ++g)
            accx[g] = MFMAH(xn, bw[g][4], bs4[g]);
    };

    for (int s2 = 0; s2 < 32; ++s2) {
        dostep(s2 * 2,     0);
        dostep(s2 * 2 + 1, 1);
    }
}

// ---------------- MLP + head for one roll: fp16 MFMA ----------
// 1024 wgs (b x 16 q-groups) x 256 thr (4 waves). wg owns 64 items (M=64).
__global__ __launch_bounds__(256, 3) void mlp_mfma_k(
    const _Float16* __restrict__ hs16, const _Float16* __restrict__ hi16,
    const float* __restrict__ r, int jstep,
    const _Float16* __restrict__ wp1, const _Float16* __restrict__ wp2,
    const _Float16* __restrict__ wp3,
    const float* __restrict__ W1, const float* __restrict__ b1,
    const float* __restrict__ b2, const float* __restrict__ b3,
    const float* __restrict__ Wf, const float* __restrict__ bfp,
    _Float16* __restrict__ cur16, float* __restrict__ out)
{
    __shared__ __align__(16) _Float16 h1f[4 * 4 * 640];   // [plane4][mt4][16x40] 20KB
    __shared__ __align__(16) _Float16 h2f[2 * 4 * 640];   // [plane2][mt4][16x40] 10KB

    const int t = threadIdx.x;
    const int w = t >> 6, l = t & 63;
    const int lrow = l & 15, lk = l >> 4;
    const int b = blockIdx.x >> 4;
    const int qb = (blockIdx.x & 15) * 64;
    const float rb = r[b * 4 + jstep];

    // ============ GEMM1: h1 = relu([hs|hi|r] @ W1^T + b1), K=256 ============
    f32x4 acc[4][2];
#pragma unroll
    for (int nt = 0; nt < 2; ++nt) {
        int col = w * 32 + nt * 16 + lrow;
        float bias = b1[col] + rb * W1[col * 257 + 256];   // fold r-col + b1 (fp32)
#pragma unroll
        for (int mt = 0; mt < 4; ++mt)
            acc[mt][nt] = (f32x4){bias, bias, bias, bias};
    }

#pragma unroll 4
    for (int kt = 0; kt < 8; ++kt) {
        half8 av[4];
#pragma unroll
        for (int mt = 0; mt < 4; ++mt) {
            int q = qb + mt * 16 + lrow;
            if (kt < 4) {        // hs part
                av[mt] = *(const half8*)(hs16 + (size_t)(b * 1024 + q) * 128
                                          + kt * 32 + lk * 8);
            } else {             // hidden_intensity part
                av[mt] = *(const half8*)(hi16 + (size_t)(b * 256 + (q >> 2)) * 128
                                          + (kt - 4) * 32 + lk * 8);
            }
        }
#pragma unroll
        for (int nt = 0; nt < 2; ++nt) {
            half8 bv = *(const half8*)(wp1 + (size_t)(kt * 8 + w * 2 + nt) * 512 + l * 8);
#pragma unroll
            for (int mt = 0; mt < 4; ++mt)
                acc[mt][nt] = MFMAH(av[mt], bv, acc[mt][nt]);
        }
    }

    // epilogue1: relu -> fp16 -> h1 plane w (wave w owns cols w*32..w*32+31)
#pragma unroll
    for (int mt = 0; mt < 4; ++mt)
#pragma unroll
        for (int nt = 0; nt < 2; ++nt)
#pragma unroll
            for (int reg = 0; reg < 4; ++reg) {
                float v = fmaxf(acc[mt][nt][reg], 0.0f);
                int s = lk * 4 + reg, jj = nt * 16 + lrow;
                h1f[(w * 4 + mt) * 640 + s * 40 + jj] = (_Float16)v;
            }
    __syncthreads();

    // ============ GEMM2: h2 = relu(h1 @ W2^T + b2), K=128, cols 16w.. =======
    f32x4 acc2[4];
    {
        float bias = b2[16 * w + lrow];
#pragma unroll
        for (int mt = 0; mt < 4; ++mt)
            acc2[mt] = (f32x4){bias, bias, bias, bias};
    }
#pragma unroll
    for (int kt = 0; kt < 4; ++kt) {
        half8 bv = *(const half8*)(wp2 + (size_t)(kt * 4 + w) * 512 + l * 8);
#pragma unroll
        for (int mt = 0; mt < 4; ++mt) {
            half8 a = *(const half8*)&h1f[(kt * 4 + mt) * 640 + lrow * 40 + lk * 8];
            acc2[mt] = MFMAH(a, bv, acc2[mt]);
        }
    }
    // epilogue2: relu -> fp16 -> h2 plane (col>>5)
#pragma unroll
    for (int mt = 0; mt < 4; ++mt)
#pragma unroll
        for (int reg = 0; reg < 4; ++reg) {
            float v = fmaxf(acc2[mt][reg], 0.0f);
            int s = lk * 4 + reg, jl2 = (w & 1) * 16 + lrow;
            h2f[((w >> 1) * 4 + mt) * 640 + s * 40 + jl2] = (_Float16)v;
        }
    __syncthreads();

    // ============ GEMM3: pr = h2 @ W3^T + b3, K=64; wave w -> rows 16w.. ===
    f32x4 acc3 = (f32x4){0.0f, 0.0f, 0.0f, 0.0f};
#pragma unroll
    for (int kt = 0; kt < 2; ++kt) {
        half8 a  = *(const half8*)&h2f[(kt * 4 + w) * 640 + lrow * 40 + lk * 8];
        half8 bv = *(const half8*)(wp3 + (size_t)kt * 512 + l * 8);
        acc3 = MFMAH(a, bv, acc3);
    }

    // epilogue3: cur16 <- fp16(pr); head: sum relu(pr)*Wf over C, then Ct
    const int c = lrow;
    const float b3v = (c < 8) ? b3[c] : 0.0f;
    const float wfv = (c < 8) ? Wf[c] : 0.0f;
    float fr[4];
#pragma unroll
    for (int reg = 0; reg < 4; ++reg) {
        float pr = acc3[reg] + b3v;
        if (c < 8) {
            int row = 16 * w + lk * 4 + reg;
            cur16[((size_t)(b * 1024 + qb + row)) * 8 + c] = (_Float16)pr;
        }
        fr[reg] = (c < 8) ? fmaxf(pr, 0.0f) * wfv : 0.0f;
    }
#pragma unroll
    for (int reg = 0; reg < 4; ++reg) {
        fr[reg] += __shfl_xor(fr[reg], 1);
        fr[reg] += __shfl_xor(fr[reg], 2);
        fr[reg] += __shfl_xor(fr[reg], 4);
    }
    if ((l & 15) == 0) {
        int n = (qb + 16 * w + lk * 4) >> 2;
        float v = fr[0] + fr[1] + fr[2] + fr[3] + 4.0f * bfp[0];
        out[(size_t)(b * 256 + n) * 4 + jstep] = v;
    }
}

extern "C" void kernel_launch(void* const* d_in, const int* in_sizes, int n_in,
                              void* d_out, int out_size, void* d_ws, size_t ws_size,
                              hipStream_t stream)
{
    const float* x   = (const float*)d_in[0];
    const float* hi  = (const float*)d_in[1];
    const float* r   = (const float*)d_in[2];
    const float* Wih = (const float*)d_in[3];
    const float* Whh = (const float*)d_in[4];
    const float* bih = (const float*)d_in[5];
    const float* bhh = (const float*)d_in[6];
    const float* W1  = (const float*)d_in[7];
    const float* b1  = (const float*)d_in[8];
    const float* W2  = (const float*)d_in[9];
    const float* b2  = (const float*)d_in[10];
    const float* W3  = (const float*)d_in[11];
    const float* b3  = (const float*)d_in[12];
    const float* Wf  = (const float*)d_in[13];
    const float* bf  = (const float*)d_in[14];
    float* out = (float*)d_out;

    _Float16* cur16 = (_Float16*)d_ws;                 // 524288
    _Float16* hs16  = cur16 + 524288;                  // 8388608 (16 MB)
    _Float16* hi16  = hs16 + 8388608;                  // 2097152
    _Float16* wp1   = hi16 + 2097152;                  // 32768
    _Float16* wp2   = wp1 + 32768;                     // 8192
    _Float16* wp3   = wp2 + 8192;                      // 1024
    _Float16* wpB   = wp3 + 1024;                      // 81920

    prep_k<<<10724, 256, 0, stream>>>(x, hi, W1, W2, W3, Whh, Wih,
                                      cur16, hi16, wp1, wp2, wp3, wpB);
    for (int j = 0; j < 4; ++j) {
        lstm_mfma_k<<<256, 512, 0, stream>>>(cur16, wpB, bih, bhh, hs16);
        mlp_mfma_k<<<1024, 256, 0, stream>>>(hs16, hi16, r, j, wp1, wp2, wp3,
                                             W1, b1, b2, b3, Wf, bf, cur16, out);
    }
}

// Round 16
// 279.316 us; speedup vs baseline: 1.0266x; 1.0266x over previous
//
#include <hip/hip_runtime.h>
#include <hip/hip_bf16.h>

// B=64 (LSTM time axis via torch batch_first quirk), L=64 (only col 63 used),
// N=256, C=8, Ct=4 -> NQ=1024 sequences, H=128, 4H=512, RH1=128, RH2=64, S=4.
//
// fp16 scheme (R14, passing at 1.95e-3): fp16 operands, fp32 accum.
// R16: (1) prep kernel vectorized x8 (was scalar, memory-bound); (2) MLP
// GEMM1 A-frag loads double-buffered (GEMM1 is load-latency-bound, 13x above
// its MFMA issue floor); (3) LSTM: gate order f-first + setprio around the
// compute region. LSTM step structure unchanged (R11-R15 falsified residency/
// conflicts/LDS-volume/load-latency/chain-depth as binding).

typedef __attribute__((ext_vector_type(8))) _Float16 half8;  // 8 f16, 4 VGPRs
typedef __attribute__((ext_vector_type(4))) float f32x4;

#define MFMAH(a, b, c) __builtin_amdgcn_mfma_f32_16x16x32_f16(a, b, c, 0, 0, 0)

__device__ __forceinline__ float sigf(float x)   { return 1.0f / (1.0f + __expf(-x)); }
__device__ __forceinline__ float tanh_f(float x) { return 1.0f - 2.0f / (__expf(2.0f * x) + 1.0f); }

// ---------------- one merged prep kernel, vectorized x8 ----------------
// vec segments (units of 8 elems): cur16 65536 | hi16 262144 -> 327680 v-jobs.
// scalar tail segments: wp1 32768 | wp2 8192 | wp3 1024 | wpB 81920 = 123904.
// total jobs = 327680 + 123904 = 451584 = 1764 * 256.
__global__ void prep_k(const float* __restrict__ x, const float* __restrict__ hi,
                       const float* __restrict__ W1, const float* __restrict__ W2,
                       const float* __restrict__ W3, const float* __restrict__ W_hh,
                       const float* __restrict__ W_ih,
                       _Float16* __restrict__ cur16, _Float16* __restrict__ hi16,
                       _Float16* __restrict__ wp1, _Float16* __restrict__ wp2,
                       _Float16* __restrict__ wp3, _Float16* __restrict__ wpB)
{
    int i = blockIdx.x * 256 + threadIdx.x;
    if (i < 65536) {                                    // cur16 <- x[:,63,:,:], 8 at a time
        int e = i * 8;
        int b = e >> 13, rem = e & 8191;
        const float* src = x + (size_t)b * 524288 + 63 * 8192 + rem;
        half8 v;
#pragma unroll
        for (int k = 0; k < 8; ++k) v[k] = (_Float16)src[k];
        *(half8*)(cur16 + e) = v;
        return;
    }
    i -= 65536;
    if (i < 262144) {                                   // hi16, 8 at a time
        int e = i * 8;
        half8 v;
#pragma unroll
        for (int k = 0; k < 8; ++k) v[k] = (_Float16)hi[e + k];
        *(half8*)(hi16 + e) = v;
        return;
    }
    i -= 262144;
    if (i < 32768) {                       // wp1 [kt8][nt8][512]; K=256 = [hs|hi]
        int fragid = i >> 9, lj = i & 511;
        int kt = fragid >> 3, nt = fragid & 7;
        int l = lj >> 3, j = lj & 7;
        int k = kt * 32 + (l >> 4) * 8 + j;
        int o = nt * 16 + (l & 15);
        wp1[i] = (_Float16)W1[o * 257 + k];
        return;
    }
    i -= 32768;
    if (i < 8192) {                        // wp2 [kt4][nt4][512]; K=128
        int fragid = i >> 9, lj = i & 511;
        int kt = fragid >> 2, nt = fragid & 3;
        int l = lj >> 3, j = lj & 7;
        int k = kt * 32 + (l >> 4) * 8 + j;
        int o = nt * 16 + (l & 15);
        wp2[i] = (_Float16)W2[o * 128 + k];
        return;
    }
    i -= 8192;
    if (i < 1024) {                        // wp3 [kt2][512]; K=64
        int kt = i >> 9, lj = i & 511;
        int l = lj >> 3, j = lj & 7;
        int k = kt * 32 + (l >> 4) * 8 + j;
        int c = l & 15;
        wp3[i] = (_Float16)((c < 8) ? W3[c * 64 + k] : 0.0f);
        return;
    }
    i -= 1024;
    if (i < 81920) {                       // wpB [kt5][ntile32][512]
        int frag = i >> 9, lj = i & 511;
        int kt = frag >> 5, ntile = frag & 31;
        int l = lj >> 3, j = lj & 7;
        int klocal = (l >> 4) * 8 + j;
        int col = ntile * 16 + (l & 15);
        float v;
        if (kt < 4) v = W_hh[col * 128 + kt * 32 + klocal];
        else        v = (klocal < 8) ? W_ih[col * 8 + klocal] : 0.0f;
        wpB[i] = (_Float16)v;
    }
}

// ---------------- LSTM scan: fp16 MFMA, 256 blocks -------------
// 256 wgs x 512 thr (8 waves = col-groups). wg owns 4 sequences at M-rows
// {0,4,8,12}. Wave cg computes gate cols g*128 + cg*16 + (l&15); gate order
// in-loop is f-first so sigf(pf)'s exp overlaps the remaining MFMA issue.
// C-reg 0 of lane (lk,li) = preact of item (seq=lk, col=cg*16+li).
// acc_x precomputed in the barrier shadow; h-chains 2||2; A-frag reads
// broadcast per 4-lane group; x staged once in LDS; hs register-direct;
// in-loop barrier drains lgkmcnt only.
__global__ __launch_bounds__(512, 2) void lstm_mfma_k(
    const _Float16* __restrict__ cur16, const _Float16* __restrict__ wpB,
    const float* __restrict__ b_ih, const float* __restrict__ b_hh,
    _Float16* __restrict__ hs16)
{
    __shared__ __align__(16) _Float16 zone[2][4][640];   // 10 KB h planes
    __shared__ __align__(16) _Float16 xz[64][32];        // 4 KB x slice

    const int t  = threadIdx.x;
    const int cg = t >> 6, l = t & 63;
    const int li = l & 15, lk = l >> 4;
    const int q0 = blockIdx.x * 4;

    // B-frags: gate order {f,i,g,o} = src gates {1,0,2,3}; 5 planes each.
    const int gsrc[4] = {1, 0, 2, 3};
    half8 bw[4][5];
#pragma unroll
    for (int g = 0; g < 4; ++g)
#pragma unroll
        for (int kt = 0; kt < 5; ++kt) {
            bw[g][kt] = *(const half8*)(wpB + (size_t)(kt * 32 + gsrc[g] * 8 + cg) * 512 + l * 8);
            asm volatile("" : "+a"(bw[g][kt]));   // pin to AGPR class, no remat
        }

    f32x4 bs4[4];
#pragma unroll
    for (int g = 0; g < 4; ++g) {
        int gc = gsrc[g] * 128 + cg * 16 + li;
        float bv = b_ih[gc] + b_hh[gc];
        bs4[g] = (f32x4){bv, bv, bv, bv};
    }

    for (int i = t; i < 1280; i += 512) ((uint*)zone)[i] = 0;   // both bufs = 0
    if (t < 256) {   // stage x slice: 64 steps x 4 seqs x 8 c = 4 KB
        int step = t >> 2, tt = t & 3;
        *(uint4*)&xz[step][tt * 8] =
            *(const uint4*)(cur16 + (size_t)step * 8192 + q0 * 8 + tt * 8);
    }
    float cc = 0.0f;
    __syncthreads();

    const int zpl   = cg >> 1;
    const int jl    = (cg & 1) * 16 + li;
    const int roff  = (li & 12) * 40 + lk * 8;   // broadcast read offset
    const int srow  = lk * 4;

    _Float16* ph = hs16 + (size_t)(q0 + lk) * 128 + cg * 16 + li;
    const _Float16* xrd = &xz[0][(li >> 2) * 8];

    f32x4 accx[4];
    {
        half8 xa0 = *(const half8*)(xrd);
#pragma unroll
        for (int g = 0; g < 4; ++g)
            accx[g] = MFMAH(xa0, bw[g][4], bs4[g]);
    }

    auto dostep = [&](int step, int p) {
        const int pn = p ^ 1;

        half8 ah[4];
#pragma unroll
        for (int kt = 0; kt < 4; ++kt)
            ah[kt] = *(const half8*)&zone[p][kt][roff];

        __builtin_amdgcn_s_setprio(1);
        const f32x4 z4 = (f32x4){0.0f, 0.0f, 0.0f, 0.0f};
        f32x4 a0[4], a1[4];
#pragma unroll
        for (int g = 0; g < 4; ++g) {          // g=0 is gate f: issued first
            a0[g] = MFMAH(ah[0], bw[g][0], accx[g]);
            a1[g] = MFMAH(ah[2], bw[g][2], z4);
        }
#pragma unroll
        for (int g = 0; g < 4; ++g) {
            a0[g] = MFMAH(ah[1], bw[g][1], a0[g]);
            a1[g] = MFMAH(ah[3], bw[g][3], a1[g]);
        }

        // gates: order {f,i,g,o}; sigf(pf) starts as soon as its pair lands
        float pf = a0[0][0] + a1[0][0];
        float sf = sigf(pf);
        float pi = a0[1][0] + a1[1][0];
        float pg = a0[2][0] + a1[2][0];
        float po = a0[3][0] + a1[3][0];
        cc = sf * cc + sigf(pi) * tanh_f(pg);
        float hv = sigf(po) * tanh_f(cc);
        __builtin_amdgcn_s_setprio(0);
        _Float16 h16 = (_Float16)hv;
        zone[pn][zpl][srow * 40 + jl] = h16;
        ph[(size_t)step * 131072] = h16;       // fire-and-forget
        asm volatile("s_waitcnt lgkmcnt(0)\n\ts_barrier" ::: "memory");

        // barrier shadow: next step's x-plane accumulation
        half8 xn = *(const half8*)(xrd + ((step + 1) & 63) * 32);
#pragma unroll
        for (int g = 0; g < 4; ++g)
            accx[g] = MFMAH(xn, bw[g][4], bs4[g]);
    };

    for (int s2 = 0; s2 < 32; ++s2) {
        dostep(s2 * 2,     0);
        dostep(s2 * 2 + 1, 1);
    }
}

// ---------------- MLP + head for one roll: fp16 MFMA ----------
// 1024 wgs (b x 16 q-groups) x 256 thr (4 waves). wg owns 64 items (M=64).
// GEMM1 A-frags double-buffered: load kt+1 while computing kt.
__global__ __launch_bounds__(256, 3) void mlp_mfma_k(
    const _Float16* __restrict__ hs16, const _Float16* __restrict__ hi16,
    const float* __restrict__ r, int jstep,
    const _Float16* __restrict__ wp1, const _Float16* __restrict__ wp2,
    const _Float16* __restrict__ wp3,
    const float* __restrict__ W1, const float* __restrict__ b1,
    const float* __restrict__ b2, const float* __restrict__ b3,
    const float* __restrict__ Wf, const float* __restrict__ bfp,
    _Float16* __restrict__ cur16, float* __restrict__ out)
{
    __shared__ __align__(16) _Float16 h1f[4 * 4 * 640];   // 20KB
    __shared__ __align__(16) _Float16 h2f[2 * 4 * 640];   // 10KB

    const int t = threadIdx.x;
    const int w = t >> 6, l = t & 63;
    const int lrow = l & 15, lk = l >> 4;
    const int b = blockIdx.x >> 4;
    const int qb = (blockIdx.x & 15) * 64;
    const float rb = r[b * 4 + jstep];

    // ============ GEMM1: h1 = relu([hs|hi|r] @ W1^T + b1), K=256 ============
    f32x4 acc[4][2];
#pragma unroll
    for (int nt = 0; nt < 2; ++nt) {
        int col = w * 32 + nt * 16 + lrow;
        float bias = b1[col] + rb * W1[col * 257 + 256];
#pragma unroll
        for (int mt = 0; mt < 4; ++mt)
            acc[mt][nt] = (f32x4){bias, bias, bias, bias};
    }

    auto loadA = [&](int kt, half8* av) {
#pragma unroll
        for (int mt = 0; mt < 4; ++mt) {
            int q = qb + mt * 16 + lrow;
            if (kt < 4)
                av[mt] = *(const half8*)(hs16 + (size_t)(b * 1024 + q) * 128
                                          + kt * 32 + lk * 8);
            else
                av[mt] = *(const half8*)(hi16 + (size_t)(b * 256 + (q >> 2)) * 128
                                          + (kt - 4) * 32 + lk * 8);
        }
    };

    half8 avA[4], avB[4];
    loadA(0, avA);
#pragma unroll
    for (int kt = 0; kt < 8; ++kt) {
        half8* cur = (kt & 1) ? avB : avA;
        half8* nxt = (kt & 1) ? avA : avB;
        if (kt < 7) loadA(kt + 1, nxt);       // prefetch next kt's A-frags
#pragma unroll
        for (int nt = 0; nt < 2; ++nt) {
            half8 bv = *(const half8*)(wp1 + (size_t)(kt * 8 + w * 2 + nt) * 512 + l * 8);
#pragma unroll
            for (int mt = 0; mt < 4; ++mt)
                acc[mt][nt] = MFMAH(cur[mt], bv, acc[mt][nt]);
        }
    }

    // epilogue1: relu -> fp16 -> h1 plane w
#pragma unroll
    for (int mt = 0; mt < 4; ++mt)
#pragma unroll
        for (int nt = 0; nt < 2; ++nt)
#pragma unroll
            for (int reg = 0; reg < 4; ++reg) {
                float v = fmaxf(acc[mt][nt][reg], 0.0f);
                int s = lk * 4 + reg, jj = nt * 16 + lrow;
                h1f[(w * 4 + mt) * 640 + s * 40 + jj] = (_Float16)v;
            }
    __syncthreads();

    // ============ GEMM2: h2 = relu(h1 @ W2^T + b2), K=128, cols 16w.. =======
    f32x4 acc2[4];
    {
        float bias = b2[16 * w + lrow];
#pragma unroll
        for (int mt = 0; mt < 4; ++mt)
            acc2[mt] = (f32x4){bias, bias, bias, bias};
    }
#pragma unroll
    for (int kt = 0; kt < 4; ++kt) {
        half8 bv = *(const half8*)(wp2 + (size_t)(kt * 4 + w) * 512 + l * 8);
#pragma unroll
        for (int mt = 0; mt < 4; ++mt) {
            half8 a = *(const half8*)&h1f[(kt * 4 + mt) * 640 + lrow * 40 + lk * 8];
            acc2[mt] = MFMAH(a, bv, acc2[mt]);
        }
    }
#pragma unroll
    for (int mt = 0; mt < 4; ++mt)
#pragma unroll
        for (int reg = 0; reg < 4; ++reg) {
            float v = fmaxf(acc2[mt][reg], 0.0f);
            int s = lk * 4 + reg, jl2 = (w & 1) * 16 + lrow;
            h2f[((w >> 1) * 4 + mt) * 640 + s * 40 + jl2] = (_Float16)v;
        }
    __syncthreads();

    // ============ GEMM3: pr = h2 @ W3^T + b3, K=64; wave w -> rows 16w.. ===
    f32x4 acc3 = (f32x4){0.0f, 0.0f, 0.0f, 0.0f};
#pragma unroll
    for (int kt = 0; kt < 2; ++kt) {
        half8 a  = *(const half8*)&h2f[(kt * 4 + w) * 640 + lrow * 40 + lk * 8];
        half8 bv = *(const half8*)(wp3 + (size_t)kt * 512 + l * 8);
        acc3 = MFMAH(a, bv, acc3);
    }

    // epilogue3: cur16 <- fp16(pr); head: sum relu(pr)*Wf over C, then Ct
    const int c = lrow;
    const float b3v = (c < 8) ? b3[c] : 0.0f;
    const float wfv = (c < 8) ? Wf[c] : 0.0f;
    float fr[4];
#pragma unroll
    for (int reg = 0; reg < 4; ++reg) {
        float pr = acc3[reg] + b3v;
        if (c < 8) {
            int row = 16 * w + lk * 4 + reg;
            cur16[((size_t)(b * 1024 + qb + row)) * 8 + c] = (_Float16)pr;
        }
        fr[reg] = (c < 8) ? fmaxf(pr, 0.0f) * wfv : 0.0f;
    }
#pragma unroll
    for (int reg = 0; reg < 4; ++reg) {
        fr[reg] += __shfl_xor(fr[reg], 1);
        fr[reg] += __shfl_xor(fr[reg], 2);
        fr[reg] += __shfl_xor(fr[reg], 4);
    }
    if ((l & 15) == 0) {
        int n = (qb + 16 * w + lk * 4) >> 2;
        float v = fr[0] + fr[1] + fr[2] + fr[3] + 4.0f * bfp[0];
        out[(size_t)(b * 256 + n) * 4 + jstep] = v;
    }
}

extern "C" void kernel_launch(void* const* d_in, const int* in_sizes, int n_in,
                              void* d_out, int out_size, void* d_ws, size_t ws_size,
                              hipStream_t stream)
{
    const float* x   = (const float*)d_in[0];
    const float* hi  = (const float*)d_in[1];
    const float* r   = (const float*)d_in[2];
    const float* Wih = (const float*)d_in[3];
    const float* Whh = (const float*)d_in[4];
    const float* bih = (const float*)d_in[5];
    const float* bhh = (const float*)d_in[6];
    const float* W1  = (const float*)d_in[7];
    const float* b1  = (const float*)d_in[8];
    const float* W2  = (const float*)d_in[9];
    const float* b2  = (const float*)d_in[10];
    const float* W3  = (const float*)d_in[11];
    const float* b3  = (const float*)d_in[12];
    const float* Wf  = (const float*)d_in[13];
    const float* bf  = (const float*)d_in[14];
    float* out = (float*)d_out;

    _Float16* cur16 = (_Float16*)d_ws;                 // 524288
    _Float16* hs16  = cur16 + 524288;                  // 8388608 (16 MB)
    _Float16* hi16  = hs16 + 8388608;                  // 2097152
    _Float16* wp1   = hi16 + 2097152;                  // 32768
    _Float16* wp2   = wp1 + 32768;                     // 8192
    _Float16* wp3   = wp2 + 8192;                      // 1024
    _Float16* wpB   = wp3 + 1024;                      // 81920

    prep_k<<<1764, 256, 0, stream>>>(x, hi, W1, W2, W3, Whh, Wih,
                                     cur16, hi16, wp1, wp2, wp3, wpB);
    for (int j = 0; j < 4; ++j) {
        lstm_mfma_k<<<256, 512, 0, stream>>>(cur16, wpB, bih, bhh, hs16);
        mlp_mfma_k<<<1024, 256, 0, stream>>>(hs16, hi16, r, j, wp1, wp2, wp3,
                                             W1, b1, b2, b3, Wf, bf, cur16, out);
    }
}